// Round 19
// baseline (3889.884 us; speedup 1.0000x reference)
//
#include <hip/hip_runtime.h>

// ICON-LM transformer forward, bf16 MFMA pipeline.
// B=16 L=750 D=1024 H=16 HD=64 NL=6 DFF=4096. Residual stream fp32, GEMMs bf16.
// Round 19: r17/r18 baseline (3862us, triple-confirmed) + ONE change: attention
// merge buffers (Om/Ml) aliased onto the Ps region (temporally disjoint, barrier-
// separated both directions) -> block LDS 18.9KB -> 10.5KB -> residency 8 -> 12
// blocks/CU for the latency-bound kernel. All else byte-identical to r17.

#define Bz  16
#define Lz  750
#define Dz  1024
#define Hz  16
#define HDz 64
#define NLz 6
#define DFFz 4096
#define Mz  (Bz*Lz)          // 12000
#define MTt 94               // ceil(12000/128) M-tiles
#define VSTRIDE 768          // padded V^T row stride (16B-aligned)
#define QKVPART ((size_t)Bz*Hz*Lz*HDz)   // 12,288,000 elems per q/k part

typedef unsigned short u16;
typedef unsigned int   u32;
typedef unsigned long long u64;
typedef __attribute__((ext_vector_type(8))) short bf8;    // 8 bf16 (4 VGPRs)
typedef __attribute__((ext_vector_type(8))) unsigned short u16x8;
typedef __attribute__((ext_vector_type(4))) float f4;
typedef __attribute__((ext_vector_type(4))) unsigned short u16x4;

__device__ __forceinline__ u16 f2b(float f){
  u32 u = __builtin_bit_cast(u32, f);
  u += 0x7fffu + ((u >> 16) & 1u);          // RNE
  return (u16)(u >> 16);
}
// two f32 -> packed bf16 pair (low = a, high = b)
__device__ __forceinline__ u32 cvtpk(float a, float b){
  u32 r;
  asm("v_cvt_pk_bf16_f32 %0, %1, %2" : "=v"(r) : "v"(a), "v"(b));
  return r;
}
__device__ __forceinline__ void glds16(const void* g, void* l){
  __builtin_amdgcn_global_load_lds((const __attribute__((address_space(1))) void*)g,
                                   (__attribute__((address_space(3))) void*)l, 16, 0, 0);
}

// ---------------- one-time mask bitmask: mb[q*12 + ktile] bit j = mask(q, ktile*64+j) ----------------
__global__ __launch_bounds__(256) void k_mask(u64* __restrict__ mb){
  const int idx = blockIdx.x*256 + threadIdx.x;
  if (idx >= Lz*12) return;
  const int q = idx / 12, kt = idx - q*12;
  const int gq = q/150, rq = q - gq*150;
  const int tq = rq < 50 ? 0 : (rq < 100 ? 1 : 2);
  u64 m = 0;
  for (int j = 0; j < 64; j++){
    const int k = kt*64 + j;
    if (k >= Lz) break;
    const int gk = k/150, rk = k - gk*150;
    const int tk = rk < 50 ? 0 : (rk < 100 ? 1 : 2);
    const bool prev = (gk < gq) && (tk < 2);
    const bool same = (gk == gq) && ((tk == 0) || (tq == 1 && tk == 1) || (tq == 2 && k == q));
    if (prev || same) m |= (1ull << j);
  }
  mb[idx] = m;
}

// ---------------- embed: x = seq @ pre_W + pre_b + pe[pos] ----------------
__global__ __launch_bounds__(256) void k_embed(const float* __restrict__ seq,
    const float* __restrict__ preW, const float* __restrict__ preb,
    const float* __restrict__ pe, float* __restrict__ x, u16* __restrict__ xb){
  const int m = blockIdx.x, t = threadIdx.x;
  const int l = m % Lz;
  const int r = l % 150;
  const int p = r < 50 ? r : (r < 100 ? r - 50 : r - 100);
  const float s0 = seq[m*5+0], s1 = seq[m*5+1], s2 = seq[m*5+2],
              s3 = seq[m*5+3], s4 = seq[m*5+4];
  const int d = t*4;
  f4 acc = *(const f4*)&preb[d];
  acc += *(const f4*)&pe[p*Dz + d];
  acc += s0 * *(const f4*)&preW[0*Dz + d];
  acc += s1 * *(const f4*)&preW[1*Dz + d];
  acc += s2 * *(const f4*)&preW[2*Dz + d];
  acc += s3 * *(const f4*)&preW[3*Dz + d];
  acc += s4 * *(const f4*)&preW[4*Dz + d];
  *(f4*)&x[(size_t)m*Dz + d] = acc;
  u16x4 hv = { f2b(acc.x), f2b(acc.y), f2b(acc.z), f2b(acc.w) };
  *(u16x4*)&xb[(size_t)m*Dz + d] = hv;
}

// ---------------- weight transpose+convert: W(KxN f32, stride ldw) -> Wt(NxK bf16) ----------------
// 64x64 tile, 256 threads. Vector f4 loads, vector u16x8 stores.
__global__ __launch_bounds__(256) void k_transpose(const float* __restrict__ W,
    u16* __restrict__ Wt, int K, int ldw){
  __shared__ float tile[64][69];
  const int t = threadIdx.x;
  const int n0 = blockIdx.x*64, k0 = blockIdx.y*64;
  const int tx = t & 15, ty = t >> 4;
  #pragma unroll
  for (int i = 0; i < 4; i++){
    const int k = ty + i*16;
    *(f4*)&tile[k][tx*4] = *(const f4*)&W[(size_t)(k0+k)*ldw + n0 + tx*4];
  }
  __syncthreads();
  const int nx = t >> 2, kq = t & 3;
  u16 buf[16];
  #pragma unroll
  for (int e = 0; e < 16; e++)
    buf[e] = f2b(tile[kq*16 + e][nx]);
  u16x8 lo = { buf[0], buf[1], buf[2], buf[3], buf[4], buf[5], buf[6], buf[7] };
  u16x8 hi = { buf[8], buf[9], buf[10], buf[11], buf[12], buf[13], buf[14], buf[15] };
  u16* dst = &Wt[(size_t)(n0 + nx)*K + k0 + kq*16];
  *(u16x8*)dst = lo;
  *(u16x8*)(dst + 8) = hi;
}

// ---------------- GEMM (TN, 128x128, 4 blocks/CU, swizzled LDS, panel-XCD map) ----------------
// C[M,N] = A[M,K](bf16,lda) @ Bt[N,K]^T + bias. 1-D grid = 12*8*NTn blocks:
// panel = id/(8*NTn); m_tile = panel*8 + id%8 (guard >= 94); n_tile = (id%(8*NTn))/8.
// XCD ~ id%8 -> each XCD reuses ONE A-tile across all N-tiles (A HBM-read once chip-wide).
// LDS: linear [128][64] u16; src granule sg^(srow&7); read granule (kk*4+g4)^(cl&7).
// EPI 0: split-scatter q/k head-major bf16, v transposed; EPI 1: x += C; EPI 2: h = bf16(gelu(C))
template<int EPI>
__global__ __launch_bounds__(256, 4) void k_gemm(
    const u16* __restrict__ A, const u16* __restrict__ Bt,
    int M, int N, int K, int lda, int ldc, int col0, int NTn,
    const float* __restrict__ bias,
    float* __restrict__ xres, u16* __restrict__ outb, u16* __restrict__ vtb){
  const int id = blockIdx.x;
  const int PN = NTn << 3;
  const int panel = id / PN, rem = id - panel*PN;
  const int mt = panel*8 + (rem & 7);
  if (mt >= MTt) return;
  const int m0 = mt*128, n0 = (rem >> 3)*128;
  __shared__ u16 As[128*64];
  __shared__ u16 Bs[128*64];
  const int t = threadIdx.x;
  const int w = t >> 6, lane = t & 63;
  const int wm = (w >> 1)*64, wn = (w & 1)*64;
  const int cl = lane & 15, g4 = lane >> 4;
  f4 acc[4][4] = {};
  const int srow = t >> 3, sg = t & 7;
  const int scol = (sg ^ (srow & 7)) * 8;   // pre-swizzled source granule
  const int lds_off = srow*64 + sg*8;       // linear LDS dest
  for (int k0 = 0; k0 < K; k0 += 64){
    #pragma unroll
    for (int c = 0; c < 4; c++){
      int ra = m0 + c*32 + srow; ra = ra < M ? ra : M-1;
      glds16(A + (size_t)ra*lda + k0 + scol, &As[c*2048 + lds_off]);
      const int rb = n0 + c*32 + srow;
      glds16(Bt + (size_t)rb*K + k0 + scol, &Bs[c*2048 + lds_off]);
    }
    __syncthreads();
    #pragma unroll
    for (int kk = 0; kk < 2; kk++){
      const int ko = ((kk*4 + g4) ^ (cl & 7)) * 8;   // swizzled read granule
      bf8 af[4], bfr[4];
      #pragma unroll
      for (int i = 0; i < 4; i++) af[i]  = *(const bf8*)&As[(wm + i*16 + cl)*64 + ko];
      #pragma unroll
      for (int j = 0; j < 4; j++) bfr[j] = *(const bf8*)&Bs[(wn + j*16 + cl)*64 + ko];
      #pragma unroll
      for (int i = 0; i < 4; i++)
        #pragma unroll
        for (int j = 0; j < 4; j++)
          acc[i][j] = __builtin_amdgcn_mfma_f32_16x16x32_bf16(af[i], bfr[j], acc[i][j], 0, 0, 0);
    }
    __syncthreads();
  }
  // epilogue: C row m = m0+wm+i*16+g4*4+r ; col n = n0+wn+j*16+cl
  const int rl = g4*4;
  #pragma unroll
  for (int i = 0; i < 4; i++){
    #pragma unroll
    for (int j = 0; j < 4; j++){
      const int gn = n0 + wn + j*16 + cl;
      const float bsv = bias ? bias[gn] : 0.f;
      if constexpr (EPI == 0){
        const int part = gn >> 10;
        const int hh = (gn >> 6) & 15;
        const int dd = gn & 63;
        const int gm0 = m0 + wm + i*16 + rl;
        if (part == 2){
          if (gm0 + 3 < M){
            const int b = gm0 / Lz, lr0 = gm0 - b*Lz;
            const float v0 = acc[i][j][0] + bsv, v1 = acc[i][j][1] + bsv;
            const float v2 = acc[i][j][2] + bsv, v3 = acc[i][j][3] + bsv;
            if (lr0 <= Lz - 4){
              u32* dst = (u32*)&vtb[((size_t)(b*Hz + hh)*HDz + dd)*VSTRIDE + lr0];
              dst[0] = cvtpk(v0, v1);
              dst[1] = cvtpk(v2, v3);
            } else {
              #pragma unroll
              for (int r = 0; r < 4; r++){
                const int gm = gm0 + r;
                const int br = gm / Lz, lr = gm - br*Lz;
                vtb[((size_t)(br*Hz + hh)*HDz + dd)*VSTRIDE + lr] = f2b(acc[i][j][r] + bsv);
              }
            }
          }
        } else {
          #pragma unroll
          for (int r = 0; r < 4; r++){
            const int gm = gm0 + r;
            if (gm < M){
              const int b = gm / Lz, lr = gm - b*Lz;
              outb[(size_t)part*QKVPART + ((size_t)(b*Hz + hh)*Lz + lr)*HDz + dd]
                  = f2b(acc[i][j][r] + bsv);
            }
          }
        }
      } else {
        #pragma unroll
        for (int r = 0; r < 4; r++){
          const int gm = m0 + wm + i*16 + rl + r;
          if (gm < M){
            const float v = acc[i][j][r] + bsv;
            if constexpr (EPI == 1){
              xres[(size_t)gm*ldc + col0 + gn] += v;
            } else {
              const float ge = 0.5f*v*(1.0f + erff(v*0.70710678f));
              outb[(size_t)gm*ldc + col0 + gn] = f2b(ge);
            }
          }
        }
      }
    }
  }
}

// ---------------- fused attention: 2-wave blocks, split-K + online-softmax merge ----------------
// grid (3072, 128 threads). id -> (xcd = id&7, j = id>>3): bh = xcd*32 + j/12, bx = j%12.
// Block handles chunk pair {bx, 23-bx}; waves interleave k-tiles (kt = wid, wid+2, ...)
// and merge (m,l,O) via LDS. Merge buffers ALIAS the Ps region (temporally disjoint,
// barrier-separated): block LDS 10.5KB -> 12 blocks/CU resident (grid-limited).
// launch_bounds (128,3): VGPR cap ~170 >= 80 measured — no spill (r14/r16 lesson).
__global__ __launch_bounds__(128, 3) void k_attn(const u16* __restrict__ qb,
    const u16* __restrict__ kb, const u16* __restrict__ vt,
    const u64* __restrict__ mb, u16* __restrict__ ob){
  // layout: [0,8192) Ps[2][1024] u32 (k-loop only)
  //         [0,9216) Om 64x36 f32   (merge only; aliases Ps — barrier-separated)
  //         [9216,10496) Ml 64x5 f32 (merge only; disjoint from Om)
  __shared__ __align__(16) char smem[10496];
  u32*   Psb = (u32*)smem;
  float* Om  = (float*)smem;
  float* Ml  = (float*)(smem + 9216);
  const int t = threadIdx.x, wid = t >> 6, lane = t & 63;
  const int cl = lane & 15, g4 = lane >> 4;
  const int id = blockIdx.x;
  const int xcd = id & 7, j = id >> 3;
  const int bh = xcd*32 + (j/12);
  const int bx = j - (j/12)*12;
  const int b = bh >> 4, h = bh & 15;
  const u16* qhp = qb + (size_t)bh*(Lz*HDz);
  const u16* khp = kb + (size_t)bh*(Lz*HDz);
  const u16* vhp = vt + (size_t)bh*(HDz*VSTRIDE);
  u32* myPs = Psb + wid*1024;
  const float SC = 0.18033688011112042f;   // 0.125 * log2(e)
  const f4 z4 = {0.f, 0.f, 0.f, 0.f};

  for (int half = 0; half < 2; half++){
    const int c = half ? (23 - bx) : bx;
    const int q0 = c*32;
    // per-lane query state (both waves identical)
    bf8 qfr[2][2];
    int qc[2];
    #pragma unroll
    for (int qf = 0; qf < 2; qf++){
      const int q = q0 + qf*16 + cl;
      qc[qf] = q < Lz ? q : Lz-1;
      #pragma unroll
      for (int kk = 0; kk < 2; kk++)
        qfr[qf][kk] = *(const bf8*)&qhp[(size_t)qc[qf]*HDz + kk*32 + g4*8];
    }
    // mask-aware tile bound (block-uniform)
    int qmax = q0 + 31; if (qmax > Lz-1) qmax = Lz-1;
    const int gqm = qmax/150;
    int kmax = gqm*150 + 100; if (qmax + 1 > kmax) kmax = qmax + 1;
    const int nt = (kmax + 63) >> 6;   // <= 12

    f4 oacc[4][2] = {};
    float mrun[2] = {-1e30f, -1e30f}, lrun[2] = {0.f, 0.f};

    for (int kt = wid; kt < nt; kt += 2){
      const int kstart = kt*64;
      // mask words for this tile (per owned q)
      u32 mlo[2], mhi[2];
      #pragma unroll
      for (int qf = 0; qf < 2; qf++){
        const u64 m = mb[qc[qf]*12 + kt];
        mlo[qf] = (u32)m; mhi[qf] = (u32)(m >> 32);
      }
      // ---- S^T = K @ Q^T ----
      f4 sacc[4][2];
      __builtin_amdgcn_s_setprio(1);
      #pragma unroll
      for (int kk = 0; kk < 2; kk++){
        bf8 kfr[4];
        #pragma unroll
        for (int kf = 0; kf < 4; kf++)
          kfr[kf] = *(const bf8*)&khp[(size_t)(kstart + kf*16 + cl)*HDz + kk*32 + g4*8];
        #pragma unroll
        for (int kf = 0; kf < 4; kf++)
          #pragma unroll
          for (int qf = 0; qf < 2; qf++)
            sacc[kf][qf] = __builtin_amdgcn_mfma_f32_16x16x32_bf16(kfr[kf], qfr[qf][kk],
                             kk == 0 ? z4 : sacc[kf][qf], 0, 0, 0);
      }
      __builtin_amdgcn_s_setprio(0);
      // ---- scale + unmasked max (mask only zeroes p; higher mn is harmless) ----
      float own0 = -1e30f, own1 = -1e30f;
      #pragma unroll
      for (int kf = 0; kf < 4; kf++){
        #pragma unroll
        for (int rr = 0; rr < 4; rr++){
          const float s0 = sacc[kf][0][rr]*SC;
          const float s1 = sacc[kf][1][rr]*SC;
          sacc[kf][0][rr] = s0; sacc[kf][1][rr] = s1;
          own0 = fmaxf(own0, s0); own1 = fmaxf(own1, s1);
        }
      }
      own0 = fmaxf(own0, __shfl_xor(own0, 16)); own0 = fmaxf(own0, __shfl_xor(own0, 32));
      own1 = fmaxf(own1, __shfl_xor(own1, 16)); own1 = fmaxf(own1, __shfl_xor(own1, 32));
      const float mn0 = fmaxf(mrun[0], own0), mn1 = fmaxf(mrun[1], own1);
      const float sc0 = exp2f(mrun[0] - mn0), sc1 = exp2f(mrun[1] - mn1);
      // ---- exp, mask-zero, sum, pack into LDS in PV B-frag order ----
      float sum0 = 0.f, sum1 = 0.f;
      #pragma unroll
      for (int kf = 0; kf < 4; kf++){
        #pragma unroll
        for (int qf = 0; qf < 2; qf++){
          const float mn = qf ? mn1 : mn0;
          const u32 w16 = ((kf & 2) ? mhi[qf] : mlo[qf]) >> ((kf & 1)*16);
          const u32 wq = w16 >> (g4*4);      // bits rr=0..3 at positions 0..3
          f4 p;
          #pragma unroll
          for (int rr = 0; rr < 4; rr++){
            const float pe = exp2f(sacc[kf][qf][rr] - mn);
            p[rr] = ((wq >> rr) & 1u) ? pe : 0.f;
            if (qf == 0) sum0 += p[rr]; else sum1 += p[rr];
          }
          const u32 lo = cvtpk(p[0], p[1]);
          const u32 hi = cvtpk(p[2], p[3]);
          const int kk = kf >> 1;
          const int tg4 = ((kf & 1) << 1) | (g4 >> 1);
          const int widx = (qf*2 + kk)*256 + tg4*64 + cl*4 + (g4 & 1)*2;
          *(u64*)&myPs[widx] = ((u64)hi << 32) | lo;
        }
      }
      sum0 += __shfl_xor(sum0, 16); sum0 += __shfl_xor(sum0, 32);
      sum1 += __shfl_xor(sum1, 16); sum1 += __shfl_xor(sum1, 32);
      lrun[0] = lrun[0]*sc0 + sum0; mrun[0] = mn0;
      lrun[1] = lrun[1]*sc1 + sum1; mrun[1] = mn1;
      // ---- rescale O ----
      #pragma unroll
      for (int df = 0; df < 4; df++){
        oacc[df][0] *= sc0;
        oacc[df][1] *= sc1;
      }
      // ---- O^T += V^T @ P ----
      __builtin_amdgcn_s_setprio(1);
      #pragma unroll
      for (int kk = 0; kk < 2; kk++){
        bf8 vfr[4];
        #pragma unroll
        for (int df = 0; df < 4; df++)
          vfr[df] = *(const bf8*)&vhp[(size_t)(df*16 + cl)*VSTRIDE + kstart + kk*32 + g4*8];
        bf8 pw[2];
        #pragma unroll
        for (int qf = 0; qf < 2; qf++)
          pw[qf] = *(const bf8*)&myPs[(qf*2 + kk)*256 + g4*64 + cl*4];
        #pragma unroll
        for (int df = 0; df < 4; df++)
          #pragma unroll
          for (int qf = 0; qf < 2; qf++)
            oacc[df][qf] = __builtin_amdgcn_mfma_f32_16x16x32_bf16(vfr[df], pw[qf], oacc[df][qf], 0, 0, 0);
      }
      __builtin_amdgcn_s_setprio(0);
    }
    // ---- merge the two waves' partial (m, l, O) and store ----
    __syncthreads();   // all Ps reads drained -> Om may alias Ps
    if (wid == 1){
      #pragma unroll
      for (int df = 0; df < 4; df++)
        #pragma unroll
        for (int qf = 0; qf < 2; qf++)
          *(f4*)&Om[lane*36 + (df*2 + qf)*4] = oacc[df][qf];
      Ml[lane*5 + 0] = mrun[0]; Ml[lane*5 + 1] = mrun[1];
      Ml[lane*5 + 2] = lrun[0]; Ml[lane*5 + 3] = lrun[1];
    }
    __syncthreads();
    if (wid == 0){
      const float m1a = Ml[lane*5 + 0], m1b = Ml[lane*5 + 1];
      const float l1a = Ml[lane*5 + 2], l1b = Ml[lane*5 + 3];
      const float M0 = fmaxf(mrun[0], m1a), M1 = fmaxf(mrun[1], m1b);
      const float sA0 = exp2f(mrun[0] - M0), sB0 = exp2f(m1a - M0);
      const float sA1 = exp2f(mrun[1] - M1), sB1 = exp2f(m1b - M1);
      const float L0 = lrun[0]*sA0 + l1a*sB0;
      const float L1 = lrun[1]*sA1 + l1b*sB1;
      const float inv0 = 1.f / L0, inv1 = 1.f / L1;
      #pragma unroll
      for (int qf = 0; qf < 2; qf++){
        const int q = q0 + qf*16 + cl;
        if (q < Lz){
          const float sA = qf ? sA1 : sA0, sB = qf ? sB1 : sB0;
          const float inv = qf ? inv1 : inv0;
          #pragma unroll
          for (int df = 0; df < 4; df++){
            const f4 o1 = *(const f4*)&Om[lane*36 + (df*2 + qf)*4];
            const f4 om = oacc[df][qf]*sA + o1*sB;
            u16x4 hv = { f2b(om[0]*inv), f2b(om[1]*inv), f2b(om[2]*inv), f2b(om[3]*inv) };
            *(u16x4*)&ob[((size_t)b*Lz + q)*Dz + h*HDz + df*16 + g4*4] = hv;
          }
        }
      }
    }
    __syncthreads();   // merge reads drained -> next half's k-loop may write Ps
  }
}

// ---------------- layernorm (in-place on fp32 x; also refresh bf16 xb) ----------------
__global__ __launch_bounds__(256) void k_ln(float* __restrict__ x, u16* __restrict__ xb,
    const float* __restrict__ g, const float* __restrict__ bb){
  const int m = blockIdx.x, t = threadIdx.x;
  float* xr = x + (size_t)m*Dz;
  f4 v = *(const f4*)&xr[t*4];
  float s = v.x + v.y + v.z + v.w;
  float q = v.x*v.x + v.y*v.y + v.z*v.z + v.w*v.w;
  #pragma unroll
  for (int off = 1; off < 64; off <<= 1){
    s += __shfl_xor(s, off);
    q += __shfl_xor(q, off);
  }
  __shared__ float ss[4], sq[4];
  const int w = t >> 6;
  if ((t & 63) == 0){ ss[w] = s; sq[w] = q; }
  __syncthreads();
  s = ss[0] + ss[1] + ss[2] + ss[3];
  q = sq[0] + sq[1] + sq[2] + sq[3];
  const float mean = s * (1.f/1024.f);
  const float var  = q * (1.f/1024.f) - mean*mean;
  const float rs = rsqrtf(var + 1e-5f);
  const f4 gg = *(const f4*)&g[t*4];
  const f4 bv = *(const f4*)&bb[t*4];
  f4 o;
  o.x = (v.x - mean)*rs*gg.x + bv.x;
  o.y = (v.y - mean)*rs*gg.y + bv.y;
  o.z = (v.z - mean)*rs*gg.z + bv.z;
  o.w = (v.w - mean)*rs*gg.w + bv.w;
  *(f4*)&xr[t*4] = o;
  u16x4 hv = { f2b(o.x), f2b(o.y), f2b(o.z), f2b(o.w) };
  *(u16x4*)&xb[(size_t)m*Dz + t*4] = hv;
}

// ---------------- final projection + gather ----------------
__global__ __launch_bounds__(64) void k_out(const float* __restrict__ x,
    const float* __restrict__ pw, const float* __restrict__ pb, float* __restrict__ out){
  const int bid = blockIdx.x, lane = threadIdx.x;   // bid = b*250 + dd*50 + qq
  const int b = bid / 250, oi = bid - b*250;
  const int dd = oi / 50, qq = oi - dd*50;
  const int l = dd*150 + 100 + qq;
  const float* xr = x + ((size_t)b*Lz + l)*Dz;
  float a0 = 0.f, a1 = 0.f;
  #pragma unroll
  for (int c = 0; c < 4; c++){
    const int d = c*256 + lane*4;
    const f4 v  = *(const f4*)&xr[d];
    const f4 p0 = *(const f4*)&pw[2*d];
    const f4 p1 = *(const f4*)&pw[2*d + 4];
    a0 += v.x*p0.x + v.y*p0.z + v.z*p1.x + v.w*p1.z;
    a1 += v.x*p0.y + v.y*p0.w + v.z*p1.y + v.w*p1.w;
  }
  #pragma unroll
  for (int off = 32; off > 0; off >>= 1){
    a0 += __shfl_xor(a0, off);
    a1 += __shfl_xor(a1, off);
  }
  if (lane == 0){
    out[(size_t)bid*2 + 0] = a0 + pb[0];
    out[(size_t)bid*2 + 1] = a1 + pb[1];
  }
}

extern "C" void kernel_launch(void* const* d_in, const int* in_sizes, int n_in,
                              void* d_out, int out_size, void* d_ws, size_t ws_size,
                              hipStream_t stream){
  (void)in_sizes; (void)n_in; (void)out_size; (void)ws_size;
  const float* seq   = (const float*)d_in[0];
  const float* preW  = (const float*)d_in[1];
  const float* preb  = (const float*)d_in[2];
  const float* pe    = (const float*)d_in[3];
  const float* Wqkv  = (const float*)d_in[4];
  const float* bqkv  = (const float*)d_in[5];
  const float* Wo    = (const float*)d_in[6];
  const float* bo    = (const float*)d_in[7];
  const float* ln1g  = (const float*)d_in[8];
  const float* ln1b  = (const float*)d_in[9];
  const float* ln2g  = (const float*)d_in[10];
  const float* ln2b  = (const float*)d_in[11];
  const float* W1    = (const float*)d_in[12];
  const float* b1    = (const float*)d_in[13];
  const float* W2    = (const float*)d_in[14];
  const float* b2    = (const float*)d_in[15];
  const float* postW = (const float*)d_in[16];
  const float* postb = (const float*)d_in[17];
  float* out = (float*)d_out;

  char* ws = (char*)d_ws;
  float* x  = (float*)(ws + 0);             // 49,152,000 B
  u16*   xb = (u16*)(ws + 49152000);        // 24,576,000 B
  u16*   R  = (u16*)(ws + 73728000);        // qB | kB | oB  (3 x 24,576,000 B)
  u16* qB = R;
  u16* kB = R + QKVPART;
  u16* oB = R + 2*QKVPART;
  u16* vT = (u16*)(ws + 147456000);         // 256*64*768*2 = 25,165,824 B
  u16* wt = (u16*)(ws + 172621824);         // 6,291,456 B  (ends 178,913,280)
  u64* mbp = (u64*)(ws + 178913280);        // 72,000 B (ends 178,985,280 < proven 180.4M)
  u16* hB = R;                              // FFN hidden [12000][4096] aliases R+vT (liveness-disjoint)

  k_mask<<<36, 256, 0, stream>>>(mbp);
  k_embed<<<Mz, 256, 0, stream>>>(seq, preW, preb, pe, x, xb);
  for (int l = 0; l < NLz; l++){
    // QKV: M=12000 N=3072 K=1024 (NT=24 -> grid 12*8*24)
    k_transpose<<<dim3(48, 16), 256, 0, stream>>>(Wqkv + (size_t)l*1024*3072, wt, 1024, 3072);
    k_gemm<0><<<12*8*24, 256, 0, stream>>>(xb, wt, Mz, 3072, 1024, 1024, 0, 0, 24,
                                           bqkv + l*3072, nullptr, qB, vT);
    // attention (2-wave blocks, split-K merge, paired chunks, XCD-confined bh mapping)
    k_attn<<<3072, 128, 0, stream>>>(qB, kB, vT, mbp, oB);
    // Wo + residual: N=1024 K=1024 (NT=8)
    k_transpose<<<dim3(16, 16), 256, 0, stream>>>(Wo + (size_t)l*1024*1024, wt, 1024, 1024);
    k_gemm<1><<<12*8*8, 256, 0, stream>>>(oB, wt, Mz, 1024, 1024, 1024, 1024, 0, 8,
                                          bo + l*1024, x, nullptr, nullptr);
    k_ln<<<Mz, 256, 0, stream>>>(x, xb, ln1g + l*1024, ln1b + l*1024);
    // FFN1: two N-halves (N=2048 each, K=1024, NT=16), wt reuse
    for (int off = 0; off < 4096; off += 2048){
      k_transpose<<<dim3(32, 16), 256, 0, stream>>>(W1 + (size_t)l*1024*4096 + off, wt, 1024, 4096);
      k_gemm<2><<<12*8*16, 256, 0, stream>>>(xb, wt, Mz, 2048, 1024, 1024, 4096, off, 16,
                                             b1 + l*4096 + off, nullptr, hB, nullptr);
    }
    // FFN2: two K-halves (N=1024, K=2048 each, NT=8) accumulating into x (bias only on first half)
    for (int koff = 0; koff < 4096; koff += 2048){
      k_transpose<<<dim3(16, 32), 256, 0, stream>>>(W2 + (size_t)l*4096*1024 + (size_t)koff*1024,
                                                    wt, 2048, 1024);
      k_gemm<1><<<12*8*8, 256, 0, stream>>>(hB + koff, wt, Mz, 1024, 2048, 4096, 1024, 0, 8,
                                            koff == 0 ? (b2 + l*1024) : nullptr, x, nullptr, nullptr);
    }
    k_ln<<<Mz, 256, 0, stream>>>(x, xb, ln2g + l*1024, ln2b + l*1024);
  }
  k_out<<<4000, 64, 0, stream>>>(x, postW, postb, out);
}

// Round 20
// 3851.543 us; speedup vs baseline: 1.0100x; 1.0100x over previous
//
#include <hip/hip_runtime.h>

// ICON-LM transformer forward, bf16 MFMA pipeline. FINAL (converged: r15/r17/r18,
// 3859/3862/3862us triple-reproduced; r19's LDS-alias variant was -28us, reverted).
// B=16 L=750 D=1024 H=16 HD=64 NL=6 DFF=4096. Residual stream fp32, GEMMs bf16.
// GEMM: 128^2, 4 blocks/CU (acc needs 64 VGPR — hard edge), XOR-swizzled LDS
// (0 bank conflicts), panel-based XCD mapping (A L2-resident per XCD).
// Attention: 2-wave split-K blocks, paired chunks (bx,23-bx), precomputed mask
// bitmask, XCD-confined bh mapping, padded merge buffers, launch_bounds(128,3).
// Tested-and-rejected: deeper GEMM pipelines (r4/r5/r11), attn reg prefetch
// (r7/r12), 5 blocks/CU GEMM (r14), (128,4) attn (r16), merge-alias LDS (r19).

#define Bz  16
#define Lz  750
#define Dz  1024
#define Hz  16
#define HDz 64
#define NLz 6
#define DFFz 4096
#define Mz  (Bz*Lz)          // 12000
#define MTt 94               // ceil(12000/128) M-tiles
#define VSTRIDE 768          // padded V^T row stride (16B-aligned)
#define QKVPART ((size_t)Bz*Hz*Lz*HDz)   // 12,288,000 elems per q/k part

typedef unsigned short u16;
typedef unsigned int   u32;
typedef unsigned long long u64;
typedef __attribute__((ext_vector_type(8))) short bf8;    // 8 bf16 (4 VGPRs)
typedef __attribute__((ext_vector_type(8))) unsigned short u16x8;
typedef __attribute__((ext_vector_type(4))) float f4;
typedef __attribute__((ext_vector_type(4))) unsigned short u16x4;

__device__ __forceinline__ u16 f2b(float f){
  u32 u = __builtin_bit_cast(u32, f);
  u += 0x7fffu + ((u >> 16) & 1u);          // RNE
  return (u16)(u >> 16);
}
// two f32 -> packed bf16 pair (low = a, high = b)
__device__ __forceinline__ u32 cvtpk(float a, float b){
  u32 r;
  asm("v_cvt_pk_bf16_f32 %0, %1, %2" : "=v"(r) : "v"(a), "v"(b));
  return r;
}
__device__ __forceinline__ void glds16(const void* g, void* l){
  __builtin_amdgcn_global_load_lds((const __attribute__((address_space(1))) void*)g,
                                   (__attribute__((address_space(3))) void*)l, 16, 0, 0);
}

// ---------------- one-time mask bitmask: mb[q*12 + ktile] bit j = mask(q, ktile*64+j) ----------------
__global__ __launch_bounds__(256) void k_mask(u64* __restrict__ mb){
  const int idx = blockIdx.x*256 + threadIdx.x;
  if (idx >= Lz*12) return;
  const int q = idx / 12, kt = idx - q*12;
  const int gq = q/150, rq = q - gq*150;
  const int tq = rq < 50 ? 0 : (rq < 100 ? 1 : 2);
  u64 m = 0;
  for (int j = 0; j < 64; j++){
    const int k = kt*64 + j;
    if (k >= Lz) break;
    const int gk = k/150, rk = k - gk*150;
    const int tk = rk < 50 ? 0 : (rk < 100 ? 1 : 2);
    const bool prev = (gk < gq) && (tk < 2);
    const bool same = (gk == gq) && ((tk == 0) || (tq == 1 && tk == 1) || (tq == 2 && k == q));
    if (prev || same) m |= (1ull << j);
  }
  mb[idx] = m;
}

// ---------------- embed: x = seq @ pre_W + pre_b + pe[pos] ----------------
__global__ __launch_bounds__(256) void k_embed(const float* __restrict__ seq,
    const float* __restrict__ preW, const float* __restrict__ preb,
    const float* __restrict__ pe, float* __restrict__ x, u16* __restrict__ xb){
  const int m = blockIdx.x, t = threadIdx.x;
  const int l = m % Lz;
  const int r = l % 150;
  const int p = r < 50 ? r : (r < 100 ? r - 50 : r - 100);
  const float s0 = seq[m*5+0], s1 = seq[m*5+1], s2 = seq[m*5+2],
              s3 = seq[m*5+3], s4 = seq[m*5+4];
  const int d = t*4;
  f4 acc = *(const f4*)&preb[d];
  acc += *(const f4*)&pe[p*Dz + d];
  acc += s0 * *(const f4*)&preW[0*Dz + d];
  acc += s1 * *(const f4*)&preW[1*Dz + d];
  acc += s2 * *(const f4*)&preW[2*Dz + d];
  acc += s3 * *(const f4*)&preW[3*Dz + d];
  acc += s4 * *(const f4*)&preW[4*Dz + d];
  *(f4*)&x[(size_t)m*Dz + d] = acc;
  u16x4 hv = { f2b(acc.x), f2b(acc.y), f2b(acc.z), f2b(acc.w) };
  *(u16x4*)&xb[(size_t)m*Dz + d] = hv;
}

// ---------------- weight transpose+convert: W(KxN f32, stride ldw) -> Wt(NxK bf16) ----------------
// 64x64 tile, 256 threads. Vector f4 loads, vector u16x8 stores.
__global__ __launch_bounds__(256) void k_transpose(const float* __restrict__ W,
    u16* __restrict__ Wt, int K, int ldw){
  __shared__ float tile[64][69];
  const int t = threadIdx.x;
  const int n0 = blockIdx.x*64, k0 = blockIdx.y*64;
  const int tx = t & 15, ty = t >> 4;
  #pragma unroll
  for (int i = 0; i < 4; i++){
    const int k = ty + i*16;
    *(f4*)&tile[k][tx*4] = *(const f4*)&W[(size_t)(k0+k)*ldw + n0 + tx*4];
  }
  __syncthreads();
  const int nx = t >> 2, kq = t & 3;
  u16 buf[16];
  #pragma unroll
  for (int e = 0; e < 16; e++)
    buf[e] = f2b(tile[kq*16 + e][nx]);
  u16x8 lo = { buf[0], buf[1], buf[2], buf[3], buf[4], buf[5], buf[6], buf[7] };
  u16x8 hi = { buf[8], buf[9], buf[10], buf[11], buf[12], buf[13], buf[14], buf[15] };
  u16* dst = &Wt[(size_t)(n0 + nx)*K + k0 + kq*16];
  *(u16x8*)dst = lo;
  *(u16x8*)(dst + 8) = hi;
}

// ---------------- GEMM (TN, 128x128, 4 blocks/CU, swizzled LDS, panel-XCD map) ----------------
// C[M,N] = A[M,K](bf16,lda) @ Bt[N,K]^T + bias. 1-D grid = 12*8*NTn blocks:
// panel = id/(8*NTn); m_tile = panel*8 + id%8 (guard >= 94); n_tile = (id%(8*NTn))/8.
// XCD ~ id%8 -> each XCD reuses ONE A-tile across all N-tiles (A HBM-read once chip-wide).
// LDS: linear [128][64] u16; src granule sg^(srow&7); read granule (kk*4+g4)^(cl&7).
// EPI 0: split-scatter q/k head-major bf16, v transposed; EPI 1: x += C; EPI 2: h = bf16(gelu(C))
template<int EPI>
__global__ __launch_bounds__(256, 4) void k_gemm(
    const u16* __restrict__ A, const u16* __restrict__ Bt,
    int M, int N, int K, int lda, int ldc, int col0, int NTn,
    const float* __restrict__ bias,
    float* __restrict__ xres, u16* __restrict__ outb, u16* __restrict__ vtb){
  const int id = blockIdx.x;
  const int PN = NTn << 3;
  const int panel = id / PN, rem = id - panel*PN;
  const int mt = panel*8 + (rem & 7);
  if (mt >= MTt) return;
  const int m0 = mt*128, n0 = (rem >> 3)*128;
  __shared__ u16 As[128*64];
  __shared__ u16 Bs[128*64];
  const int t = threadIdx.x;
  const int w = t >> 6, lane = t & 63;
  const int wm = (w >> 1)*64, wn = (w & 1)*64;
  const int cl = lane & 15, g4 = lane >> 4;
  f4 acc[4][4] = {};
  const int srow = t >> 3, sg = t & 7;
  const int scol = (sg ^ (srow & 7)) * 8;   // pre-swizzled source granule
  const int lds_off = srow*64 + sg*8;       // linear LDS dest
  for (int k0 = 0; k0 < K; k0 += 64){
    #pragma unroll
    for (int c = 0; c < 4; c++){
      int ra = m0 + c*32 + srow; ra = ra < M ? ra : M-1;
      glds16(A + (size_t)ra*lda + k0 + scol, &As[c*2048 + lds_off]);
      const int rb = n0 + c*32 + srow;
      glds16(Bt + (size_t)rb*K + k0 + scol, &Bs[c*2048 + lds_off]);
    }
    __syncthreads();
    #pragma unroll
    for (int kk = 0; kk < 2; kk++){
      const int ko = ((kk*4 + g4) ^ (cl & 7)) * 8;   // swizzled read granule
      bf8 af[4], bfr[4];
      #pragma unroll
      for (int i = 0; i < 4; i++) af[i]  = *(const bf8*)&As[(wm + i*16 + cl)*64 + ko];
      #pragma unroll
      for (int j = 0; j < 4; j++) bfr[j] = *(const bf8*)&Bs[(wn + j*16 + cl)*64 + ko];
      #pragma unroll
      for (int i = 0; i < 4; i++)
        #pragma unroll
        for (int j = 0; j < 4; j++)
          acc[i][j] = __builtin_amdgcn_mfma_f32_16x16x32_bf16(af[i], bfr[j], acc[i][j], 0, 0, 0);
    }
    __syncthreads();
  }
  // epilogue: C row m = m0+wm+i*16+g4*4+r ; col n = n0+wn+j*16+cl
  const int rl = g4*4;
  #pragma unroll
  for (int i = 0; i < 4; i++){
    #pragma unroll
    for (int j = 0; j < 4; j++){
      const int gn = n0 + wn + j*16 + cl;
      const float bsv = bias ? bias[gn] : 0.f;
      if constexpr (EPI == 0){
        const int part = gn >> 10;
        const int hh = (gn >> 6) & 15;
        const int dd = gn & 63;
        const int gm0 = m0 + wm + i*16 + rl;
        if (part == 2){
          if (gm0 + 3 < M){
            const int b = gm0 / Lz, lr0 = gm0 - b*Lz;
            const float v0 = acc[i][j][0] + bsv, v1 = acc[i][j][1] + bsv;
            const float v2 = acc[i][j][2] + bsv, v3 = acc[i][j][3] + bsv;
            if (lr0 <= Lz - 4){
              u32* dst = (u32*)&vtb[((size_t)(b*Hz + hh)*HDz + dd)*VSTRIDE + lr0];
              dst[0] = cvtpk(v0, v1);
              dst[1] = cvtpk(v2, v3);
            } else {
              #pragma unroll
              for (int r = 0; r < 4; r++){
                const int gm = gm0 + r;
                const int br = gm / Lz, lr = gm - br*Lz;
                vtb[((size_t)(br*Hz + hh)*HDz + dd)*VSTRIDE + lr] = f2b(acc[i][j][r] + bsv);
              }
            }
          }
        } else {
          #pragma unroll
          for (int r = 0; r < 4; r++){
            const int gm = gm0 + r;
            if (gm < M){
              const int b = gm / Lz, lr = gm - b*Lz;
              outb[(size_t)part*QKVPART + ((size_t)(b*Hz + hh)*Lz + lr)*HDz + dd]
                  = f2b(acc[i][j][r] + bsv);
            }
          }
        }
      } else {
        #pragma unroll
        for (int r = 0; r < 4; r++){
          const int gm = m0 + wm + i*16 + rl + r;
          if (gm < M){
            const float v = acc[i][j][r] + bsv;
            if constexpr (EPI == 1){
              xres[(size_t)gm*ldc + col0 + gn] += v;
            } else {
              const float ge = 0.5f*v*(1.0f + erff(v*0.70710678f));
              outb[(size_t)gm*ldc + col0 + gn] = f2b(ge);
            }
          }
        }
      }
    }
  }
}

// ---------------- fused attention: 2-wave blocks, split-K + online-softmax merge ----------------
// grid (3072, 128 threads). id -> (xcd = id&7, j = id>>3): bh = xcd*32 + j/12, bx = j%12.
// Block handles chunk pair {bx, 23-bx}; within a chunk the two waves interleave
// k-tiles (kt = wid, wid+2, ...) and merge (m,l,O) via padded LDS (no bank conflicts).
// launch_bounds (128,3): VGPR cap ~170 >= 80 measured — no spill (r14/r16 lesson).
__global__ __launch_bounds__(128, 3) void k_attn(const u16* __restrict__ qb,
    const u16* __restrict__ kb, const u16* __restrict__ vt,
    const u64* __restrict__ mb, u16* __restrict__ ob){
  __shared__ u32 Ps[2][1024];     // per-wave P permute buffer (4KB each)
  __shared__ float Om[64*36];     // wave1 O fragments, stride 36 (bank-rotating)
  __shared__ float Ml[64*5];      // wave1 m0,m1,l0,l1, stride 5 (bank-rotating)
  const int t = threadIdx.x, wid = t >> 6, lane = t & 63;
  const int cl = lane & 15, g4 = lane >> 4;
  const int id = blockIdx.x;
  const int xcd = id & 7, j = id >> 3;
  const int bh = xcd*32 + (j/12);
  const int bx = j - (j/12)*12;
  const int b = bh >> 4, h = bh & 15;
  const u16* qhp = qb + (size_t)bh*(Lz*HDz);
  const u16* khp = kb + (size_t)bh*(Lz*HDz);
  const u16* vhp = vt + (size_t)bh*(HDz*VSTRIDE);
  u32* myPs = &Ps[wid][0];
  const float SC = 0.18033688011112042f;   // 0.125 * log2(e)
  const f4 z4 = {0.f, 0.f, 0.f, 0.f};

  for (int half = 0; half < 2; half++){
    const int c = half ? (23 - bx) : bx;
    const int q0 = c*32;
    // per-lane query state (both waves identical)
    bf8 qfr[2][2];
    int qc[2];
    #pragma unroll
    for (int qf = 0; qf < 2; qf++){
      const int q = q0 + qf*16 + cl;
      qc[qf] = q < Lz ? q : Lz-1;
      #pragma unroll
      for (int kk = 0; kk < 2; kk++)
        qfr[qf][kk] = *(const bf8*)&qhp[(size_t)qc[qf]*HDz + kk*32 + g4*8];
    }
    // mask-aware tile bound (block-uniform)
    int qmax = q0 + 31; if (qmax > Lz-1) qmax = Lz-1;
    const int gqm = qmax/150;
    int kmax = gqm*150 + 100; if (qmax + 1 > kmax) kmax = qmax + 1;
    const int nt = (kmax + 63) >> 6;   // <= 12

    f4 oacc[4][2] = {};
    float mrun[2] = {-1e30f, -1e30f}, lrun[2] = {0.f, 0.f};

    for (int kt = wid; kt < nt; kt += 2){
      const int kstart = kt*64;
      // mask words for this tile (per owned q)
      u32 mlo[2], mhi[2];
      #pragma unroll
      for (int qf = 0; qf < 2; qf++){
        const u64 m = mb[qc[qf]*12 + kt];
        mlo[qf] = (u32)m; mhi[qf] = (u32)(m >> 32);
      }
      // ---- S^T = K @ Q^T ----
      f4 sacc[4][2];
      __builtin_amdgcn_s_setprio(1);
      #pragma unroll
      for (int kk = 0; kk < 2; kk++){
        bf8 kfr[4];
        #pragma unroll
        for (int kf = 0; kf < 4; kf++)
          kfr[kf] = *(const bf8*)&khp[(size_t)(kstart + kf*16 + cl)*HDz + kk*32 + g4*8];
        #pragma unroll
        for (int kf = 0; kf < 4; kf++)
          #pragma unroll
          for (int qf = 0; qf < 2; qf++)
            sacc[kf][qf] = __builtin_amdgcn_mfma_f32_16x16x32_bf16(kfr[kf], qfr[qf][kk],
                             kk == 0 ? z4 : sacc[kf][qf], 0, 0, 0);
      }
      __builtin_amdgcn_s_setprio(0);
      // ---- scale + unmasked max (mask only zeroes p; higher mn is harmless) ----
      float own0 = -1e30f, own1 = -1e30f;
      #pragma unroll
      for (int kf = 0; kf < 4; kf++){
        #pragma unroll
        for (int rr = 0; rr < 4; rr++){
          const float s0 = sacc[kf][0][rr]*SC;
          const float s1 = sacc[kf][1][rr]*SC;
          sacc[kf][0][rr] = s0; sacc[kf][1][rr] = s1;
          own0 = fmaxf(own0, s0); own1 = fmaxf(own1, s1);
        }
      }
      own0 = fmaxf(own0, __shfl_xor(own0, 16)); own0 = fmaxf(own0, __shfl_xor(own0, 32));
      own1 = fmaxf(own1, __shfl_xor(own1, 16)); own1 = fmaxf(own1, __shfl_xor(own1, 32));
      const float mn0 = fmaxf(mrun[0], own0), mn1 = fmaxf(mrun[1], own1);
      const float sc0 = exp2f(mrun[0] - mn0), sc1 = exp2f(mrun[1] - mn1);
      // ---- exp, mask-zero, sum, pack into LDS in PV B-frag order ----
      float sum0 = 0.f, sum1 = 0.f;
      #pragma unroll
      for (int kf = 0; kf < 4; kf++){
        #pragma unroll
        for (int qf = 0; qf < 2; qf++){
          const float mn = qf ? mn1 : mn0;
          const u32 w16 = ((kf & 2) ? mhi[qf] : mlo[qf]) >> ((kf & 1)*16);
          const u32 wq = w16 >> (g4*4);      // bits rr=0..3 at positions 0..3
          f4 p;
          #pragma unroll
          for (int rr = 0; rr < 4; rr++){
            const float pe = exp2f(sacc[kf][qf][rr] - mn);
            p[rr] = ((wq >> rr) & 1u) ? pe : 0.f;
            if (qf == 0) sum0 += p[rr]; else sum1 += p[rr];
          }
          const u32 lo = cvtpk(p[0], p[1]);
          const u32 hi = cvtpk(p[2], p[3]);
          const int kk = kf >> 1;
          const int tg4 = ((kf & 1) << 1) | (g4 >> 1);
          const int widx = (qf*2 + kk)*256 + tg4*64 + cl*4 + (g4 & 1)*2;
          *(u64*)&myPs[widx] = ((u64)hi << 32) | lo;
        }
      }
      sum0 += __shfl_xor(sum0, 16); sum0 += __shfl_xor(sum0, 32);
      sum1 += __shfl_xor(sum1, 16); sum1 += __shfl_xor(sum1, 32);
      lrun[0] = lrun[0]*sc0 + sum0; mrun[0] = mn0;
      lrun[1] = lrun[1]*sc1 + sum1; mrun[1] = mn1;
      // ---- rescale O ----
      #pragma unroll
      for (int df = 0; df < 4; df++){
        oacc[df][0] *= sc0;
        oacc[df][1] *= sc1;
      }
      // ---- O^T += V^T @ P ----
      __builtin_amdgcn_s_setprio(1);
      #pragma unroll
      for (int kk = 0; kk < 2; kk++){
        bf8 vfr[4];
        #pragma unroll
        for (int df = 0; df < 4; df++)
          vfr[df] = *(const bf8*)&vhp[(size_t)(df*16 + cl)*VSTRIDE + kstart + kk*32 + g4*8];
        bf8 pw[2];
        #pragma unroll
        for (int qf = 0; qf < 2; qf++)
          pw[qf] = *(const bf8*)&myPs[(qf*2 + kk)*256 + g4*64 + cl*4];
        #pragma unroll
        for (int df = 0; df < 4; df++)
          #pragma unroll
          for (int qf = 0; qf < 2; qf++)
            oacc[df][qf] = __builtin_amdgcn_mfma_f32_16x16x32_bf16(vfr[df], pw[qf], oacc[df][qf], 0, 0, 0);
      }
      __builtin_amdgcn_s_setprio(0);
    }
    // ---- merge the two waves' partial (m, l, O) and store ----
    __syncthreads();
    if (wid == 1){
      #pragma unroll
      for (int df = 0; df < 4; df++)
        #pragma unroll
        for (int qf = 0; qf < 2; qf++)
          *(f4*)&Om[lane*36 + (df*2 + qf)*4] = oacc[df][qf];
      Ml[lane*5 + 0] = mrun[0]; Ml[lane*5 + 1] = mrun[1];
      Ml[lane*5 + 2] = lrun[0]; Ml[lane*5 + 3] = lrun[1];
    }
    __syncthreads();
    if (wid == 0){
      const float m1a = Ml[lane*5 + 0], m1b = Ml[lane*5 + 1];
      const float l1a = Ml[lane*5 + 2], l1b = Ml[lane*5 + 3];
      const float M0 = fmaxf(mrun[0], m1a), M1 = fmaxf(mrun[1], m1b);
      const float sA0 = exp2f(mrun[0] - M0), sB0 = exp2f(m1a - M0);
      const float sA1 = exp2f(mrun[1] - M1), sB1 = exp2f(m1b - M1);
      const float L0 = lrun[0]*sA0 + l1a*sB0;
      const float L1 = lrun[1]*sA1 + l1b*sB1;
      const float inv0 = 1.f / L0, inv1 = 1.f / L1;
      #pragma unroll
      for (int qf = 0; qf < 2; qf++){
        const int q = q0 + qf*16 + cl;
        if (q < Lz){
          const float sA = qf ? sA1 : sA0, sB = qf ? sB1 : sB0;
          const float inv = qf ? inv1 : inv0;
          #pragma unroll
          for (int df = 0; df < 4; df++){
            const f4 o1 = *(const f4*)&Om[lane*36 + (df*2 + qf)*4];
            const f4 om = oacc[df][qf]*sA + o1*sB;
            u16x4 hv = { f2b(om[0]*inv), f2b(om[1]*inv), f2b(om[2]*inv), f2b(om[3]*inv) };
            *(u16x4*)&ob[((size_t)b*Lz + q)*Dz + h*HDz + df*16 + g4*4] = hv;
          }
        }
      }
    }
    __syncthreads();   // merge buffers free before next half
  }
}

// ---------------- layernorm (in-place on fp32 x; also refresh bf16 xb) ----------------
__global__ __launch_bounds__(256) void k_ln(float* __restrict__ x, u16* __restrict__ xb,
    const float* __restrict__ g, const float* __restrict__ bb){
  const int m = blockIdx.x, t = threadIdx.x;
  float* xr = x + (size_t)m*Dz;
  f4 v = *(const f4*)&xr[t*4];
  float s = v.x + v.y + v.z + v.w;
  float q = v.x*v.x + v.y*v.y + v.z*v.z + v.w*v.w;
  #pragma unroll
  for (int off = 1; off < 64; off <<= 1){
    s += __shfl_xor(s, off);
    q += __shfl_xor(q, off);
  }
  __shared__ float ss[4], sq[4];
  const int w = t >> 6;
  if ((t & 63) == 0){ ss[w] = s; sq[w] = q; }
  __syncthreads();
  s = ss[0] + ss[1] + ss[2] + ss[3];
  q = sq[0] + sq[1] + sq[2] + sq[3];
  const float mean = s * (1.f/1024.f);
  const float var  = q * (1.f/1024.f) - mean*mean;
  const float rs = rsqrtf(var + 1e-5f);
  const f4 gg = *(const f4*)&g[t*4];
  const f4 bv = *(const f4*)&bb[t*4];
  f4 o;
  o.x = (v.x - mean)*rs*gg.x + bv.x;
  o.y = (v.y - mean)*rs*gg.y + bv.y;
  o.z = (v.z - mean)*rs*gg.z + bv.z;
  o.w = (v.w - mean)*rs*gg.w + bv.w;
  *(f4*)&xr[t*4] = o;
  u16x4 hv = { f2b(o.x), f2b(o.y), f2b(o.z), f2b(o.w) };
  *(u16x4*)&xb[(size_t)m*Dz + t*4] = hv;
}

// ---------------- final projection + gather ----------------
__global__ __launch_bounds__(64) void k_out(const float* __restrict__ x,
    const float* __restrict__ pw, const float* __restrict__ pb, float* __restrict__ out){
  const int bid = blockIdx.x, lane = threadIdx.x;   // bid = b*250 + dd*50 + qq
  const int b = bid / 250, oi = bid - b*250;
  const int dd = oi / 50, qq = oi - dd*50;
  const int l = dd*150 + 100 + qq;
  const float* xr = x + ((size_t)b*Lz + l)*Dz;
  float a0 = 0.f, a1 = 0.f;
  #pragma unroll
  for (int c = 0; c < 4; c++){
    const int d = c*256 + lane*4;
    const f4 v  = *(const f4*)&xr[d];
    const f4 p0 = *(const f4*)&pw[2*d];
    const f4 p1 = *(const f4*)&pw[2*d + 4];
    a0 += v.x*p0.x + v.y*p0.z + v.z*p1.x + v.w*p1.z;
    a1 += v.x*p0.y + v.y*p0.w + v.z*p1.y + v.w*p1.w;
  }
  #pragma unroll
  for (int off = 32; off > 0; off >>= 1){
    a0 += __shfl_xor(a0, off);
    a1 += __shfl_xor(a1, off);
  }
  if (lane == 0){
    out[(size_t)bid*2 + 0] = a0 + pb[0];
    out[(size_t)bid*2 + 1] = a1 + pb[1];
  }
}

extern "C" void kernel_launch(void* const* d_in, const int* in_sizes, int n_in,
                              void* d_out, int out_size, void* d_ws, size_t ws_size,
                              hipStream_t stream){
  (void)in_sizes; (void)n_in; (void)out_size; (void)ws_size;
  const float* seq   = (const float*)d_in[0];
  const float* preW  = (const float*)d_in[1];
  const float* preb  = (const float*)d_in[2];
  const float* pe    = (const float*)d_in[3];
  const float* Wqkv  = (const float*)d_in[4];
  const float* bqkv  = (const float*)d_in[5];
  const float* Wo    = (const float*)d_in[6];
  const float* bo    = (const float*)d_in[7];
  const float* ln1g  = (const float*)d_in[8];
  const float* ln1b  = (const float*)d_in[9];
  const float* ln2g  = (const float*)d_in[10];
  const float* ln2b  = (const float*)d_in[11];
  const float* W1    = (const float*)d_in[12];
  const float* b1    = (const float*)d_in[13];
  const float* W2    = (const float*)d_in[14];
  const float* b2    = (const float*)d_in[15];
  const float* postW = (const float*)d_in[16];
  const float* postb = (const float*)d_in[17];
  float* out = (float*)d_out;

  char* ws = (char*)d_ws;
  float* x  = (float*)(ws + 0);             // 49,152,000 B
  u16*   xb = (u16*)(ws + 49152000);        // 24,576,000 B
  u16*   R  = (u16*)(ws + 73728000);        // qB | kB | oB  (3 x 24,576,000 B)
  u16* qB = R;
  u16* kB = R + QKVPART;
  u16* oB = R + 2*QKVPART;
  u16* vT = (u16*)(ws + 147456000);         // 256*64*768*2 = 25,165,824 B
  u16* wt = (u16*)(ws + 172621824);         // 6,291,456 B  (ends 178,913,280)
  u64* mbp = (u64*)(ws + 178913280);        // 72,000 B (ends 178,985,280 < proven 180.4M)
  u16* hB = R;                              // FFN hidden [12000][4096] aliases R+vT (liveness-disjoint)

  k_mask<<<36, 256, 0, stream>>>(mbp);
  k_embed<<<Mz, 256, 0, stream>>>(seq, preW, preb, pe, x, xb);
  for (int l = 0; l < NLz; l++){
    // QKV: M=12000 N=3072 K=1024 (NT=24 -> grid 12*8*24)
    k_transpose<<<dim3(48, 16), 256, 0, stream>>>(Wqkv + (size_t)l*1024*3072, wt, 1024, 3072);
    k_gemm<0><<<12*8*24, 256, 0, stream>>>(xb, wt, Mz, 3072, 1024, 1024, 0, 0, 24,
                                           bqkv + l*3072, nullptr, qB, vT);
    // attention (2-wave blocks, split-K merge, paired chunks, XCD-confined bh mapping)
    k_attn<<<3072, 128, 0, stream>>>(qB, kB, vT, mbp, oB);
    // Wo + residual: N=1024 K=1024 (NT=8)
    k_transpose<<<dim3(16, 16), 256, 0, stream>>>(Wo + (size_t)l*1024*1024, wt, 1024, 1024);
    k_gemm<1><<<12*8*8, 256, 0, stream>>>(oB, wt, Mz, 1024, 1024, 1024, 1024, 0, 8,
                                          bo + l*1024, x, nullptr, nullptr);
    k_ln<<<Mz, 256, 0, stream>>>(x, xb, ln1g + l*1024, ln1b + l*1024);
    // FFN1: two N-halves (N=2048 each, K=1024, NT=16), wt reuse
    for (int off = 0; off < 4096; off += 2048){
      k_transpose<<<dim3(32, 16), 256, 0, stream>>>(W1 + (size_t)l*1024*4096 + off, wt, 1024, 4096);
      k_gemm<2><<<12*8*16, 256, 0, stream>>>(xb, wt, Mz, 2048, 1024, 1024, 4096, off, 16,
                                             b1 + l*4096 + off, nullptr, hB, nullptr);
    }
    // FFN2: two K-halves (N=1024, K=2048 each, NT=8) accumulating into x (bias only on first half)
    for (int koff = 0; koff < 4096; koff += 2048){
      k_transpose<<<dim3(16, 32), 256, 0, stream>>>(W2 + (size_t)l*4096*1024 + (size_t)koff*1024,
                                                    wt, 2048, 1024);
      k_gemm<1><<<12*8*8, 256, 0, stream>>>(hB + koff, wt, Mz, 1024, 2048, 4096, 1024, 0, 8,
                                            koff == 0 ? (b2 + l*1024) : nullptr, x, nullptr, nullptr);
    }
    k_ln<<<Mz, 256, 0, stream>>>(x, xb, ln2g + l*1024, ln2b + l*1024);
  }
  k_out<<<4000, 64, 0, stream>>>(x, postW, postb, out);
}